// Round 3
// baseline (187.060 us; speedup 1.0000x reference)
//
#include <hip/hip_runtime.h>

// Problem constants (reference: BATCH=8192, IN_F=2048, OUT_F=2048)
#define M_DIM 8192
#define N_DIM 2048
#define K_DIM 2048
#define LN2F 0.69314718055994530942f
#define LOG2EF 1.44269504088896340736f
#define BIAS_PHI 0.62009741f  // softplus(1) - ln2 = log((1+e)/2)

typedef _Float16 f16x8 __attribute__((ext_vector_type(8)));
typedef float f32x4 __attribute__((ext_vector_type(4)));

// ---------------------------------------------------------------------------
// softplus(x) - ln2 via native v_exp_f32 (2^x) and v_log_f32 (log2):
//   t = x*log2e;  r = (log2(1 + 2^t) - 1) * ln2
// t >= 24: 2^t dominates -> r = x - ln2. t << 0: 2^t -> 0 -> r = -ln2 (ok).
// ---------------------------------------------------------------------------
__device__ __forceinline__ float softplus_m_ln2(float v) {
    float t = v * LOG2EF;
    float e = __builtin_amdgcn_exp2f(t);
    float r = (__builtin_amdgcn_logf(1.0f + e) - 1.0f) * LN2F;
    return t < 24.0f ? r : v - LN2F;
}

// ---------------------------------------------------------------------------
// Fused prep (UNCHANGED): blocks [0,8192) do phi; [8192,10240) do W rows.
// ---------------------------------------------------------------------------
__global__ __launch_bounds__(256) void prep_kernel(const float* __restrict__ x,
                                                   const float* __restrict__ W,
                                                   _Float16* __restrict__ phi,
                                                   _Float16* __restrict__ Wh,
                                                   float* __restrict__ bias) {
    if (blockIdx.x < 8192) {
        size_t i = ((size_t)blockIdx.x * blockDim.x + threadIdx.x) * 8;
        float4 v0 = *(const float4*)(x + i);
        float4 v1 = *(const float4*)(x + i + 4);
        union { _Float16 h[8]; uint4 u; } pk;
        pk.h[0] = (_Float16)softplus_m_ln2(v0.x);
        pk.h[1] = (_Float16)softplus_m_ln2(v0.y);
        pk.h[2] = (_Float16)softplus_m_ln2(v0.z);
        pk.h[3] = (_Float16)softplus_m_ln2(v0.w);
        pk.h[4] = (_Float16)softplus_m_ln2(v1.x);
        pk.h[5] = (_Float16)softplus_m_ln2(v1.y);
        pk.h[6] = (_Float16)softplus_m_ln2(v1.z);
        pk.h[7] = (_Float16)softplus_m_ln2(v1.w);
        *(uint4*)(phi + i) = pk.u;
    } else {
        const int o = blockIdx.x - 8192;
        const float* row = W + (size_t)o * (K_DIM + 1) + threadIdx.x * 8;
        union { _Float16 h[8]; uint4 u; } pk;
#pragma unroll
        for (int j = 0; j < 8; ++j)
            pk.h[j] = (_Float16)row[j];
        *(uint4*)(Wh + (size_t)o * K_DIM + threadIdx.x * 8) = pk.u;
        if (threadIdx.x == 0)
            bias[o] = W[(size_t)o * (K_DIM + 1) + K_DIM] * BIAS_PHI;
    }
}

// ---------------------------------------------------------------------------
// GEMM: C[m,n] = sum_k phi[m,k] * Wh[n,k] + bias[n]
//
// R8: R5/R6/R7 all ~72 us regardless of staging schedule -> staging was
// never the critical path. Arithmetic: per K-tile per CU, MFMA pipe ~620
// cyc but LDS-read pipe ~750-1150 cyc (192 ds_read_b128); R7's per-phase
// {reads -> barrier -> lgkmcnt(0) -> MFMA} SERIALIZES the two pipes ->
// 38% MfmaUtil == 620/1634 measured. Fix: software-pipeline ds_reads one
// phase ahead and let the COMPILER insert counted lgkm waits (all reads
// are C++ loads, deps tracked), so phase p's MFMA overlaps phase p+1's
// LDS drain. Only the 2 hazard-carrying fences per K-tile remain:
//   order: R_P1(12) GLL_A0 R_P2(8) [MFMA_P1 || R_P2 drain] GLL_A1
//          vmcnt(4) barrier          <- B1(t) landed for everyone
//          R_P3(4) [MFMA_P2 || R_P3 drain] GLL_B0 MFMA_P3 GLL_B1 MFMA_P4
//          vmcnt(2) barrier          <- A0/A1/B0(t+1) landed; B1 in flight
// All cur-buffer reads retire before the tile-end barrier (last reads =
// bfr1, waited before MFMA_P3) -> GLLs into cur issued next tile are safe.
// Loads are kc-outer so counted lgkm overlaps even within P1. vmcnt
// ledger (2 loads per GLL pair): 2 ->A0 4 ->A1 6 ->wait4 ->B0 6 ->B1 8
// ->wait2; never 0 in-loop; t=31 peels to vmcnt(0)/skip.
//
// XOR swizzle (verified conflict-free, SQ_LDS_BANK_CONFLICT=0 R2-R7):
// row = 64 f16 = 8 chunks of 16 B; physical chunk = logical ^ (row & 7).
// ---------------------------------------------------------------------------
#define GLL(gp, lp)                                                                     \
    __builtin_amdgcn_global_load_lds((const __attribute__((address_space(1))) void*)(gp), \
                                     (__attribute__((address_space(3))) void*)(lp), 16, 0, 0)

__global__ __launch_bounds__(512, 2) void kan_gemm(const _Float16* __restrict__ A,  // M x K
                                                   const _Float16* __restrict__ B,  // N x K
                                                   const float* __restrict__ bias,  // N
                                                   float* __restrict__ C) {         // M x N
    __shared__ __align__(16) _Float16 sA[2][256 * 64];  // 64 KB
    __shared__ __align__(16) _Float16 sB[2][256 * 64];  // 64 KB

    const int tid  = threadIdx.x;
    const int lane = tid & 63;
    const int wv   = tid >> 6;   // wave 0..7
    const int wm   = wv >> 2;    // 0..1: M half (128 rows)
    const int wn   = wv & 3;     // 0..3: N quarter (64 cols)

    const size_t Arow0 = (size_t)blockIdx.x * 256;
    const size_t Bcol0 = (size_t)blockIdx.y * 256;

    // Staging lane pattern: one issue = 8 rows x 64 cols. Lane l -> row
    // r8=l>>3, physical chunk l&7, fetches logical chunk (l&7)^r8.
    const int r8 = lane >> 3;
    const int lc = (lane & 7) ^ r8;

    // Half-tile-aligned dst rows (16 groups of 8 rows per operand-half):
    //   A-half0 rows = [0,64)+[128,192): g -> (g>>3)*128 + (g&7)*8
    //   B-half0 rows = [0,32)+[64,96)+[128,160)+[192,224): g -> (g>>2)*64+(g&3)*8
    const int g0 = wv * 2, g1 = wv * 2 + 1;
    const int rA[4] = {(g0 >> 3) * 128 + (g0 & 7) * 8,
                       (g1 >> 3) * 128 + (g1 & 7) * 8,
                       (g0 >> 3) * 128 + (g0 & 7) * 8 + 64,
                       (g1 >> 3) * 128 + (g1 & 7) * 8 + 64};
    const int rB[4] = {(g0 >> 2) * 64 + (g0 & 3) * 8,
                       (g1 >> 2) * 64 + (g1 & 3) * 8,
                       (g0 >> 2) * 64 + (g0 & 3) * 8 + 32,
                       (g1 >> 2) * 64 + (g1 & 3) * 8 + 32};
    const _Float16* gAj[4];
    const _Float16* gBj[4];
#pragma unroll
    for (int j = 0; j < 4; ++j) {
        gAj[j] = A + (Arow0 + rA[j] + r8) * (size_t)K_DIM + lc * 8;
        gBj[j] = B + (Bcol0 + rB[j] + r8) * (size_t)K_DIM + lc * 8;
    }

    // MFMA operand addressing: outer idx = lane&15, logical chunk
    // c = (lane>>4) + 4*kc; physical = c ^ (lr & 7); kc=1 -> XOR 32 elems.
    const int lr   = lane & 15;
    const int kph0 = ((lane >> 4) ^ (lr & 7)) * 8;

    f32x4 acc[8][4];  // [qm*4+mi][qn*2+ni]
#pragma unroll
    for (int i = 0; i < 8; ++i)
#pragma unroll
        for (int j = 0; j < 4; ++j)
            acc[i][j] = (f32x4){0.0f, 0.0f, 0.0f, 0.0f};

    // ---- prologue: stage tile 0 into buffer 0, full drain once
#pragma unroll
    for (int j = 0; j < 4; ++j)
        GLL(gAj[j], &sA[0][rA[j] * 64]);
#pragma unroll
    for (int j = 0; j < 4; ++j)
        GLL(gBj[j], &sB[0][rB[j] * 64]);
    asm volatile("s_waitcnt vmcnt(0)" ::: "memory");
    __builtin_amdgcn_s_barrier();

    f16x8 afr0[4][2], afr1[4][2];  // qm=0 / qm=1 A-frags x 2 k-slices
    f16x8 bfr0[2][2], bfr1[2][2];  // qn=0 / qn=1 B-frags x 2 k-slices

    for (int t = 0; t < 32; ++t) {
        const int d = t & 1;
        const _Float16* sAd = sA[d];
        const _Float16* sBd = sB[d];
        _Float16* dA = sA[d ^ 1];
        _Float16* dB = sB[d ^ 1];
        const size_t kn = (size_t)(t + 1) * 64;
        const bool more = (t + 1) < 32;

        // ---- R_P1: afr0 + bfr0, kc-outer (12 ds_read_b128) ----
#pragma unroll
        for (int kc = 0; kc < 2; ++kc) {
#pragma unroll
            for (int mi = 0; mi < 4; ++mi)
                afr0[mi][kc] = *(const f16x8*)&sAd[(wm * 128 + mi * 16 + lr) * 64 + (kph0 ^ (kc * 32))];
#pragma unroll
            for (int ni = 0; ni < 2; ++ni)
                bfr0[ni][kc] = *(const f16x8*)&sBd[(wn * 64 + ni * 16 + lr) * 64 + (kph0 ^ (kc * 32))];
        }
        if (more) {
            GLL(gAj[0] + kn, &dA[rA[0] * 64]);
            GLL(gAj[1] + kn, &dA[rA[1] * 64]);
        }
        // ---- R_P2: afr1, kc-outer (8 reads) — drains under MFMA_P1 ----
#pragma unroll
        for (int kc = 0; kc < 2; ++kc)
#pragma unroll
            for (int mi = 0; mi < 4; ++mi)
                afr1[mi][kc] = *(const f16x8*)&sAd[(wm * 128 + 64 + mi * 16 + lr) * 64 + (kph0 ^ (kc * 32))];

        // ---- MFMA_P1 (qm0,qn0): compiler waits only afr0/bfr0 ----
        __builtin_amdgcn_s_setprio(1);
#pragma unroll
        for (int kc = 0; kc < 2; ++kc)
#pragma unroll
            for (int mi = 0; mi < 4; ++mi)
#pragma unroll
                for (int ni = 0; ni < 2; ++ni)
                    acc[mi][ni] = __builtin_amdgcn_mfma_f32_16x16x32_f16(
                        afr0[mi][kc], bfr0[ni][kc], acc[mi][ni], 0, 0, 0);
        __builtin_amdgcn_s_setprio(0);
        if (more) {
            GLL(gAj[2] + kn, &dA[rA[2] * 64]);
            GLL(gAj[3] + kn, &dA[rA[3] * 64]);
        }

        // ---- mid-tile fence: B1(t) landed for everyone ----
        if (more)
            asm volatile("s_waitcnt vmcnt(4)" ::: "memory");
        else
            asm volatile("s_waitcnt vmcnt(0)" ::: "memory");
        __builtin_amdgcn_s_barrier();

        // ---- R_P3: bfr1, kc-outer (4 reads) — drains under MFMA_P2 ----
#pragma unroll
        for (int kc = 0; kc < 2; ++kc)
#pragma unroll
            for (int ni = 0; ni < 2; ++ni)
                bfr1[ni][kc] = *(const f16x8*)&sBd[(wn * 64 + 32 + ni * 16 + lr) * 64 + (kph0 ^ (kc * 32))];

        // ---- MFMA_P2 (qm1,qn0): waits afr1 only ----
        __builtin_amdgcn_s_setprio(1);
#pragma unroll
        for (int kc = 0; kc < 2; ++kc)
#pragma unroll
            for (int mi = 0; mi < 4; ++mi)
#pragma unroll
                for (int ni = 0; ni < 2; ++ni)
                    acc[4 + mi][ni] = __builtin_amdgcn_mfma_f32_16x16x32_f16(
                        afr1[mi][kc], bfr0[ni][kc], acc[4 + mi][ni], 0, 0, 0);
        __builtin_amdgcn_s_setprio(0);
        if (more) {
            GLL(gBj[0] + kn, &dB[rB[0] * 64]);
            GLL(gBj[1] + kn, &dB[rB[1] * 64]);
        }

        // ---- MFMA_P3 (qm1,qn1): waits bfr1 ----
        __builtin_amdgcn_s_setprio(1);
#pragma unroll
        for (int kc = 0; kc < 2; ++kc)
#pragma unroll
            for (int mi = 0; mi < 4; ++mi)
#pragma unroll
                for (int ni = 0; ni < 2; ++ni)
                    acc[4 + mi][2 + ni] = __builtin_amdgcn_mfma_f32_16x16x32_f16(
                        afr1[mi][kc], bfr1[ni][kc], acc[4 + mi][2 + ni], 0, 0, 0);
        __builtin_amdgcn_s_setprio(0);
        if (more) {
            GLL(gBj[2] + kn, &dB[rB[2] * 64]);
            GLL(gBj[3] + kn, &dB[rB[3] * 64]);
        }

        // ---- MFMA_P4 (qm0,qn1): all operands already waited ----
        __builtin_amdgcn_s_setprio(1);
#pragma unroll
        for (int kc = 0; kc < 2; ++kc)
#pragma unroll
            for (int mi = 0; mi < 4; ++mi)
#pragma unroll
                for (int ni = 0; ni < 2; ++ni)
                    acc[mi][2 + ni] = __builtin_amdgcn_mfma_f32_16x16x32_f16(
                        afr0[mi][kc], bfr1[ni][kc], acc[mi][2 + ni], 0, 0, 0);
        __builtin_amdgcn_s_setprio(0);

        // ---- tile-end fence: A0/A1/B0(t+1) landed; B1(t+1) stays in
        // flight (retired by next tile's mid fence). All cur reads retired
        // above -> next tile's GLLs into cur are safe after this barrier.
        if (more)
            asm volatile("s_waitcnt vmcnt(2)" ::: "memory");
        __builtin_amdgcn_s_barrier();
    }

    // Epilogue. C/D layout: col(n) = lane&15, row(m) = (lane>>4)*4 + reg.
    // acc[ai][bj]: row = wm*128 + (ai>>2)*64 + (ai&3)*16, col = wn*64 +
    // (bj>>1)*32 + (bj&1)*16.
    const int crow = (lane >> 4) * 4;
    float bsv[4];
#pragma unroll
    for (int bj = 0; bj < 4; ++bj)
        bsv[bj] = bias[Bcol0 + wn * 64 + (bj >> 1) * 32 + (bj & 1) * 16 + lr];

#pragma unroll
    for (int ai = 0; ai < 8; ++ai) {
#pragma unroll
        for (int r = 0; r < 4; ++r) {
            float* cp = C + (Arow0 + wm * 128 + (ai >> 2) * 64 + (ai & 3) * 16 + crow + r) * (size_t)N_DIM
                        + Bcol0 + wn * 64 + lr;
#pragma unroll
            for (int bj = 0; bj < 4; ++bj)
                cp[(bj >> 1) * 32 + (bj & 1) * 16] = acc[ai][bj][r] + bsv[bj];
        }
    }
}

// ---------------------------------------------------------------------------
extern "C" void kernel_launch(void* const* d_in, const int* in_sizes, int n_in,
                              void* d_out, int out_size, void* d_ws, size_t ws_size,
                              hipStream_t stream) {
    const float* x = (const float*)d_in[0];   // (8192, 2048) fp32
    const float* W = (const float*)d_in[1];   // (2048, 2049) fp32
    float* out = (float*)d_out;               // (8192, 2048) fp32

    // workspace layout: phi (M*K f16) | Wh (N*K f16) | bias (N f32)  ~42 MB
    char* ws = (char*)d_ws;
    _Float16* phi = (_Float16*)ws;
    _Float16* Wh  = (_Float16*)(ws + (size_t)M_DIM * K_DIM * sizeof(_Float16));
    float* bias   = (float*)(ws + (size_t)M_DIM * K_DIM * sizeof(_Float16)
                                + (size_t)N_DIM * K_DIM * sizeof(_Float16));

    prep_kernel<<<8192 + 2048, 256, 0, stream>>>(x, W, phi, Wh, bias);
    dim3 grid(M_DIM / 256, N_DIM / 256);  // 32 x 8 = 256 blocks, 1/CU
    kan_gemm<<<grid, 512, 0, stream>>>(phi, Wh, bias, out);
}

// Round 4
// 186.587 us; speedup vs baseline: 1.0025x; 1.0025x over previous
//
#include <hip/hip_runtime.h>

// Problem constants (reference: BATCH=8192, IN_F=2048, OUT_F=2048)
#define M_DIM 8192
#define N_DIM 2048
#define K_DIM 2048
#define LN2F 0.69314718055994530942f
#define LOG2EF 1.44269504088896340736f
#define BIAS_PHI 0.62009741f  // softplus(1) - ln2 = log((1+e)/2)

typedef _Float16 f16x8 __attribute__((ext_vector_type(8)));
typedef float f32x4 __attribute__((ext_vector_type(4)));

// ---------------------------------------------------------------------------
// softplus(x) - ln2 via native v_exp_f32 (2^x) and v_log_f32 (log2):
//   t = x*log2e;  r = (log2(1 + 2^t) - 1) * ln2
// t >= 24: 2^t dominates -> r = x - ln2. t << 0: 2^t -> 0 -> r = -ln2 (ok).
// ---------------------------------------------------------------------------
__device__ __forceinline__ float softplus_m_ln2(float v) {
    float t = v * LOG2EF;
    float e = __builtin_amdgcn_exp2f(t);
    float r = (__builtin_amdgcn_logf(1.0f + e) - 1.0f) * LN2F;
    return t < 24.0f ? r : v - LN2F;
}

// ---------------------------------------------------------------------------
// Fused prep (UNCHANGED): blocks [0,8192) do phi; [8192,10240) do W rows.
// ---------------------------------------------------------------------------
__global__ __launch_bounds__(256) void prep_kernel(const float* __restrict__ x,
                                                   const float* __restrict__ W,
                                                   _Float16* __restrict__ phi,
                                                   _Float16* __restrict__ Wh,
                                                   float* __restrict__ bias) {
    if (blockIdx.x < 8192) {
        size_t i = ((size_t)blockIdx.x * blockDim.x + threadIdx.x) * 8;
        float4 v0 = *(const float4*)(x + i);
        float4 v1 = *(const float4*)(x + i + 4);
        union { _Float16 h[8]; uint4 u; } pk;
        pk.h[0] = (_Float16)softplus_m_ln2(v0.x);
        pk.h[1] = (_Float16)softplus_m_ln2(v0.y);
        pk.h[2] = (_Float16)softplus_m_ln2(v0.z);
        pk.h[3] = (_Float16)softplus_m_ln2(v0.w);
        pk.h[4] = (_Float16)softplus_m_ln2(v1.x);
        pk.h[5] = (_Float16)softplus_m_ln2(v1.y);
        pk.h[6] = (_Float16)softplus_m_ln2(v1.z);
        pk.h[7] = (_Float16)softplus_m_ln2(v1.w);
        *(uint4*)(phi + i) = pk.u;
    } else {
        const int o = blockIdx.x - 8192;
        const float* row = W + (size_t)o * (K_DIM + 1) + threadIdx.x * 8;
        union { _Float16 h[8]; uint4 u; } pk;
#pragma unroll
        for (int j = 0; j < 8; ++j)
            pk.h[j] = (_Float16)row[j];
        *(uint4*)(Wh + (size_t)o * K_DIM + threadIdx.x * 8) = pk.u;
        if (threadIdx.x == 0)
            bias[o] = W[(size_t)o * (K_DIM + 1) + K_DIM] * BIAS_PHI;
    }
}

// ---------------------------------------------------------------------------
// GEMM: C[m,n] = sum_k phi[m,k] * Wh[n,k] + bias[n]
//
// R9: full m201 cadence. Geometry unchanged (256x256 tile, BK=64, 8 waves
// 2Mx4N, wave 128x64, acc[8][4]). 2 K-tiles per iteration (even->buf0,
// odd->buf1), 8 phases/iter; each phase:
//   {ds_reads | 1 half-tile prefetch (2 GLL) | barrier | lgkmcnt(0) |
//    setprio(1) 16 MFMA setprio(0) | counted vmcnt | barrier}
// Halves (match frag reads): A0'=rows[0,64)+[128,192), A1'=+64;
// B0'=cols stripes [0,32)+64k, B1'=+32. Phase p consumes, frees at its 2nd
// barrier; prefetch issue stream (1 half/phase, per wave = 2 GLL):
//   ph0:b1(t1) ph1:a0(t0+2) ph2:b0(t0+2) ph3:a1(t0+2) ph4:b1(t0+2)
//   ph5:a0(t1+2) ph6:b0(t1+2) ph7:a1(t1+2)
// Every half is written >=1 phase after its region's free-barrier, and
// consumed 6-7 phases after issue. Wait ledger (per wave, 2 loads/half):
// uniform vmcnt(10) (=5 halves in flight) at end of ph0,1,3,4,5,7; none
// at ph2,6. Wait sits BEFORE the 2nd barrier so DMA-landings are
// published cross-wave (vmcnt is per-wave!). Never 0 in the main loop.
// Prologue: 7 halves (a0b0a1b1(0), a0b0a1(1)) + vmcnt(10). Final iter
// peeled: no prefetch except ph0's b1(31); waits 10/8/-/4/2/0.
//
// XOR swizzle (conflict-free, SQ_LDS_BANK_CONFLICT=0 R2-R8) unchanged:
// row = 8 chunks of 16 B; physical chunk = logical ^ (row & 7).
// ---------------------------------------------------------------------------
#define GLL(gp, lp)                                                                     \
    __builtin_amdgcn_global_load_lds((const __attribute__((address_space(1))) void*)(gp), \
                                     (__attribute__((address_space(3))) void*)(lp), 16, 0, 0)

#define BAR   __builtin_amdgcn_s_barrier()
#define LGKM0 asm volatile("s_waitcnt lgkmcnt(0)" ::: "memory")
#define VM(n) asm volatile("s_waitcnt vmcnt(" #n ")" ::: "memory")
#define PRIO1 __builtin_amdgcn_s_setprio(1)
#define PRIO0 __builtin_amdgcn_s_setprio(0)

// ds_reads: 4x2 A-frags / 2x2 B-frags, kc-outer
#define READ_A(dst, d, roff)                                                             \
    _Pragma("unroll") for (int kc = 0; kc < 2; ++kc)                                     \
    _Pragma("unroll") for (int mi = 0; mi < 4; ++mi)                                     \
        dst[mi][kc] = *(const f16x8*)&sA[d][(wm * 128 + (roff) + mi * 16 + lr) * 64 + (kph0 ^ (kc * 32))];

#define READ_B(dst, d, coff)                                                             \
    _Pragma("unroll") for (int kc = 0; kc < 2; ++kc)                                     \
    _Pragma("unroll") for (int ni = 0; ni < 2; ++ni)                                     \
        dst[ni][kc] = *(const f16x8*)&sB[d][(wn * 64 + (coff) + ni * 16 + lr) * 64 + (kph0 ^ (kc * 32))];

// one C-quadrant: 16 MFMA
#define MFMA_Q(AF, BF, AI, BJ)                                                           \
    _Pragma("unroll") for (int kc = 0; kc < 2; ++kc)                                     \
    _Pragma("unroll") for (int mi = 0; mi < 4; ++mi)                                     \
    _Pragma("unroll") for (int ni = 0; ni < 2; ++ni)                                     \
        acc[(AI) + mi][(BJ) + ni] = __builtin_amdgcn_mfma_f32_16x16x32_f16(              \
            AF[mi][kc], BF[ni][kc], acc[(AI) + mi][(BJ) + ni], 0, 0, 0);

// one half-tile prefetch = 2 GLL (per wave)
#define GLL_A(half, buf, kt)                                                             \
    do {                                                                                 \
        GLL(gAj[2 * (half)] + (size_t)(kt) * 64, &sA[buf][rA[2 * (half)] * 64]);         \
        GLL(gAj[2 * (half) + 1] + (size_t)(kt) * 64, &sA[buf][rA[2 * (half) + 1] * 64]); \
    } while (0)
#define GLL_B(half, buf, kt)                                                             \
    do {                                                                                 \
        GLL(gBj[2 * (half)] + (size_t)(kt) * 64, &sB[buf][rB[2 * (half)] * 64]);         \
        GLL(gBj[2 * (half) + 1] + (size_t)(kt) * 64, &sB[buf][rB[2 * (half) + 1] * 64]); \
    } while (0)

__global__ __launch_bounds__(512, 2) void kan_gemm(const _Float16* __restrict__ A,  // M x K
                                                   const _Float16* __restrict__ B,  // N x K
                                                   const float* __restrict__ bias,  // N
                                                   float* __restrict__ C) {         // M x N
    __shared__ __align__(16) _Float16 sA[2][256 * 64];  // 64 KB
    __shared__ __align__(16) _Float16 sB[2][256 * 64];  // 64 KB

    const int tid  = threadIdx.x;
    const int lane = tid & 63;
    const int wv   = tid >> 6;   // wave 0..7
    const int wm   = wv >> 2;    // 0..1: M half (128 rows)
    const int wn   = wv & 3;     // 0..3: N quarter (64 cols)

    const size_t Arow0 = (size_t)blockIdx.x * 256;
    const size_t Bcol0 = (size_t)blockIdx.y * 256;

    // Staging lane pattern: one issue = 8 rows x 64 cols. Lane l -> row
    // r8=l>>3, physical chunk l&7, fetches logical chunk (l&7)^r8.
    const int r8 = lane >> 3;
    const int lc = (lane & 7) ^ r8;

    // Half-tile dst rows (wave wv's 2 groups per half):
    //   A-half0 rows = [0,64)+[128,192): g -> (g>>3)*128 + (g&7)*8
    //   B-half0 rows = [0,32)+[64,96)+...: g -> (g>>2)*64 + (g&3)*8
    const int g0 = wv * 2, g1 = wv * 2 + 1;
    const int rA[4] = {(g0 >> 3) * 128 + (g0 & 7) * 8,
                       (g1 >> 3) * 128 + (g1 & 7) * 8,
                       (g0 >> 3) * 128 + (g0 & 7) * 8 + 64,
                       (g1 >> 3) * 128 + (g1 & 7) * 8 + 64};
    const int rB[4] = {(g0 >> 2) * 64 + (g0 & 3) * 8,
                       (g1 >> 2) * 64 + (g1 & 3) * 8,
                       (g0 >> 2) * 64 + (g0 & 3) * 8 + 32,
                       (g1 >> 2) * 64 + (g1 & 3) * 8 + 32};
    const _Float16* gAj[4];
    const _Float16* gBj[4];
#pragma unroll
    for (int j = 0; j < 4; ++j) {
        gAj[j] = A + (Arow0 + rA[j] + r8) * (size_t)K_DIM + lc * 8;
        gBj[j] = B + (Bcol0 + rB[j] + r8) * (size_t)K_DIM + lc * 8;
    }

    // MFMA operand addressing: outer idx = lane&15, logical chunk
    // c = (lane>>4) + 4*kc; physical = c ^ (lr & 7); kc=1 -> XOR 32 elems.
    const int lr   = lane & 15;
    const int kph0 = ((lane >> 4) ^ (lr & 7)) * 8;

    f32x4 acc[8][4];  // [qm*4+mi][qn*2+ni]
#pragma unroll
    for (int i = 0; i < 8; ++i)
#pragma unroll
        for (int j = 0; j < 4; ++j)
            acc[i][j] = (f32x4){0.0f, 0.0f, 0.0f, 0.0f};

    f16x8 afr0[4][2], afr1[4][2];  // A rows +0 / +64
    f16x8 bfr0[2][2], bfr1[2][2];  // B cols +0 / +32

    // ---- prologue: 7 halves in ledger order; b1(1) comes at iter0.ph0
    GLL_A(0, 0, 0); GLL_B(0, 0, 0); GLL_A(1, 0, 0); GLL_B(1, 0, 0);
    GLL_A(0, 1, 1); GLL_B(0, 1, 1); GLL_A(1, 1, 1);
    VM(10); BAR;

    for (int i = 0; i < 15; ++i) {
        const int t1 = 2 * i + 1;
        const int n0 = 2 * i + 2, n1 = 2 * i + 3;
        // ph0: t0 Q(0,0)
        READ_A(afr0, 0, 0); READ_B(bfr0, 0, 0);
        GLL_B(1, 1, t1);
        BAR; LGKM0; PRIO1; MFMA_Q(afr0, bfr0, 0, 0); PRIO0; VM(10); BAR;
        // ph1: t0 Q(1,0)
        READ_A(afr1, 0, 64);
        GLL_A(0, 0, n0);
        BAR; LGKM0; PRIO1; MFMA_Q(afr1, bfr0, 4, 0); PRIO0; VM(10); BAR;
        // ph2: t0 Q(1,1)
        READ_B(bfr1, 0, 32);
        GLL_B(0, 0, n0);
        BAR; LGKM0; PRIO1; MFMA_Q(afr1, bfr1, 4, 2); PRIO0; BAR;
        // ph3: t0 Q(0,1) — no reads
        GLL_A(1, 0, n0);
        BAR; PRIO1; MFMA_Q(afr0, bfr1, 0, 2); PRIO0; VM(10); BAR;
        // ph4: t1 Q(0,0)
        READ_A(afr0, 1, 0); READ_B(bfr0, 1, 0);
        GLL_B(1, 0, n0);
        BAR; LGKM0; PRIO1; MFMA_Q(afr0, bfr0, 0, 0); PRIO0; VM(10); BAR;
        // ph5: t1 Q(1,0)
        READ_A(afr1, 1, 64);
        GLL_A(0, 1, n1);
        BAR; LGKM0; PRIO1; MFMA_Q(afr1, bfr0, 4, 0); PRIO0; VM(10); BAR;
        // ph6: t1 Q(1,1)
        READ_B(bfr1, 1, 32);
        GLL_B(0, 1, n1);
        BAR; LGKM0; PRIO1; MFMA_Q(afr1, bfr1, 4, 2); PRIO0; BAR;
        // ph7: t1 Q(0,1) — no reads
        GLL_A(1, 1, n1);
        BAR; PRIO1; MFMA_Q(afr0, bfr1, 0, 2); PRIO0; VM(10); BAR;
    }

    // ---- peeled final iteration (t0=30, t1=31): only ph0's b1(31) issues;
    // waits tighten 10/8/-/4/2/0 per the ledger.
    {
        READ_A(afr0, 0, 0); READ_B(bfr0, 0, 0);
        GLL_B(1, 1, 31);
        BAR; LGKM0; PRIO1; MFMA_Q(afr0, bfr0, 0, 0); PRIO0; VM(10); BAR;

        READ_A(afr1, 0, 64);
        BAR; LGKM0; PRIO1; MFMA_Q(afr1, bfr0, 4, 0); PRIO0; VM(8); BAR;

        READ_B(bfr1, 0, 32);
        BAR; LGKM0; PRIO1; MFMA_Q(afr1, bfr1, 4, 2); PRIO0; BAR;

        BAR; PRIO1; MFMA_Q(afr0, bfr1, 0, 2); PRIO0; VM(4); BAR;

        READ_A(afr0, 1, 0); READ_B(bfr0, 1, 0);
        BAR; LGKM0; PRIO1; MFMA_Q(afr0, bfr0, 0, 0); PRIO0; VM(2); BAR;

        READ_A(afr1, 1, 64);
        BAR; LGKM0; PRIO1; MFMA_Q(afr1, bfr0, 4, 0); PRIO0; VM(0); BAR;

        READ_B(bfr1, 1, 32);
        BAR; LGKM0; PRIO1; MFMA_Q(afr1, bfr1, 4, 2); PRIO0; BAR;

        BAR; PRIO1; MFMA_Q(afr0, bfr1, 0, 2); PRIO0;
    }

    // Epilogue. C/D layout: col(n) = lane&15, row(m) = (lane>>4)*4 + reg.
    // acc[ai][bj]: row = wm*128 + (ai>>2)*64 + (ai&3)*16, col = wn*64 +
    // (bj>>1)*32 + (bj&1)*16.
    const int crow = (lane >> 4) * 4;
    float bsv[4];
#pragma unroll
    for (int bj = 0; bj < 4; ++bj)
        bsv[bj] = bias[Bcol0 + wn * 64 + (bj >> 1) * 32 + (bj & 1) * 16 + lr];

#pragma unroll
    for (int ai = 0; ai < 8; ++ai) {
#pragma unroll
        for (int r = 0; r < 4; ++r) {
            float* cp = C + (Arow0 + wm * 128 + (ai >> 2) * 64 + (ai & 3) * 16 + crow + r) * (size_t)N_DIM
                        + Bcol0 + wn * 64 + lr;
#pragma unroll
            for (int bj = 0; bj < 4; ++bj)
                cp[(bj >> 1) * 32 + (bj & 1) * 16] = acc[ai][bj][r] + bsv[bj];
        }
    }
}

// ---------------------------------------------------------------------------
extern "C" void kernel_launch(void* const* d_in, const int* in_sizes, int n_in,
                              void* d_out, int out_size, void* d_ws, size_t ws_size,
                              hipStream_t stream) {
    const float* x = (const float*)d_in[0];   // (8192, 2048) fp32
    const float* W = (const float*)d_in[1];   // (2048, 2049) fp32
    float* out = (float*)d_out;               // (8192, 2048) fp32

    // workspace layout: phi (M*K f16) | Wh (N*K f16) | bias (N f32)  ~42 MB
    char* ws = (char*)d_ws;
    _Float16* phi = (_Float16*)ws;
    _Float16* Wh  = (_Float16*)(ws + (size_t)M_DIM * K_DIM * sizeof(_Float16));
    float* bias   = (float*)(ws + (size_t)M_DIM * K_DIM * sizeof(_Float16)
                                + (size_t)N_DIM * K_DIM * sizeof(_Float16));

    prep_kernel<<<8192 + 2048, 256, 0, stream>>>(x, W, phi, Wh, bias);
    dim3 grid(M_DIM / 256, N_DIM / 256);  // 32 x 8 = 256 blocks, 1/CU
    kan_gemm<<<grid, 512, 0, stream>>>(phi, Wh, bias, out);
}